// Round 1
// baseline (135.357 us; speedup 1.0000x reference)
//
#include <hip/hip_runtime.h>
#include <stdint.h>

// ---------------------------------------------------------------------------
// BalanceCrossEntropyLoss (OHEM top-K) via histogram selection.
// N=16, H=W=640. All three inputs flat-aligned, 6,553,600 f32 elements each.
//
// negative losses = -clip(log(1-p), -100) are strictly positive floats in
// ~(0.01, 4.61); positive-float bit patterns are monotone, so a
// (exponent, top-7-mantissa) histogram over exponents 2^-7 .. 2^3 (1280 bins)
// gives an order-exact partition. Top-K sum = full bins above threshold bin
// + remaining * (bin mean). Worst-case output error ~6e-5 << 3.45e-2 tol.
// ---------------------------------------------------------------------------

#define TOT   (16 * 640 * 640)
#define NV    (TOT / 4)          // float4 elements (TOT % 4 == 0)
#define MBITS 7                  // mantissa bits kept per exponent
#define NEXP  10                 // exponents 0x78..0x81  (2^-7 .. 2^3)
#define E0    0x78
#define NBINS (NEXP << MBITS)    // 1280
#define BLOCK 256
#define GRID1 512
#define BPT   (NBINS / BLOCK)    // 5 bins per thread in the scan kernel

__device__ __forceinline__ int bin_of(float loss) {
    uint32_t b = __float_as_uint(loss);
    int e = (int)(b >> 23) - E0;
    int m = (int)((b >> (23 - MBITS)) & ((1u << MBITS) - 1u));
    int idx = (e << MBITS) + m;
    if (e < 0) idx = 0;                 // underflow -> lowest bin
    if (idx > NBINS - 1) idx = NBINS - 1; // overflow -> top bin
    return idx;
}

__global__ __launch_bounds__(BLOCK) void bce_pass1(
        const float4* __restrict__ pred,
        const float4* __restrict__ gt,
        const float4* __restrict__ mask,
        uint32_t* __restrict__ g_cnt,   // [NBINS]
        float*    __restrict__ g_sum,   // [NBINS]
        uint32_t* __restrict__ g_pos_cnt,
        float*    __restrict__ g_pos_sum) {
    __shared__ uint32_t s_cnt[NBINS];
    __shared__ float    s_sum[NBINS];
    __shared__ uint32_t s_pc;
    __shared__ float    s_ps;

    const int tid = threadIdx.x;
    for (int i = tid; i < NBINS; i += BLOCK) { s_cnt[i] = 0u; s_sum[i] = 0.f; }
    if (tid == 0) { s_pc = 0u; s_ps = 0.f; }
    __syncthreads();

    uint32_t lpc = 0; float lps = 0.f;
    const int stride = gridDim.x * BLOCK;
    for (int i = blockIdx.x * BLOCK + tid; i < NV; i += stride) {
        float4 p4 = pred[i], g4 = gt[i], m4 = mask[i];
        float pp[4] = {p4.x, p4.y, p4.z, p4.w};
        float gg[4] = {g4.x, g4.y, g4.z, g4.w};
        float mm[4] = {m4.x, m4.y, m4.z, m4.w};
#pragma unroll
        for (int j = 0; j < 4; ++j) {
            bool m = mm[j] > 0.5f;     // mask/gt are exactly 0.0f or 1.0f
            bool g = gg[j] > 0.5f;
            if (!m) continue;
            // gt==1 -> loss = -clip(log p, -100); gt==0 -> -clip(log(1-p),-100)
            float x = g ? pp[j] : (1.0f - pp[j]);
            float l = -fmaxf(__logf(x), -100.0f);
            if (g) {
                lpc++; lps += l;
            } else {
                int b = bin_of(l);
                atomicAdd(&s_cnt[b], 1u);
                __hip_atomic_fetch_add(&s_sum[b], l, __ATOMIC_RELAXED,
                                       __HIP_MEMORY_SCOPE_WORKGROUP);
            }
        }
    }
    atomicAdd(&s_pc, lpc);
    __hip_atomic_fetch_add(&s_ps, lps, __ATOMIC_RELAXED,
                           __HIP_MEMORY_SCOPE_WORKGROUP);
    __syncthreads();

    // flush block histogram (skip empty bins to cut global atomics ~2x)
    for (int i = tid; i < NBINS; i += BLOCK) {
        uint32_t c = s_cnt[i];
        if (c) {
            atomicAdd(&g_cnt[i], c);
            __hip_atomic_fetch_add(&g_sum[i], s_sum[i], __ATOMIC_RELAXED,
                                   __HIP_MEMORY_SCOPE_AGENT);
        }
    }
    if (tid == 0) {
        atomicAdd(g_pos_cnt, s_pc);
        __hip_atomic_fetch_add(g_pos_sum, s_ps, __ATOMIC_RELAXED,
                               __HIP_MEMORY_SCOPE_AGENT);
    }
}

__global__ __launch_bounds__(BLOCK) void bce_pass2(
        const uint32_t* __restrict__ g_cnt,
        const float*    __restrict__ g_sum,
        const uint32_t* __restrict__ g_pos_cnt,
        const float*    __restrict__ g_pos_sum,
        float* __restrict__ out) {
    __shared__ uint32_t scnt[BLOCK];
    __shared__ float    ssum[BLOCK];
    __shared__ float    s_negsum;

    const int t = threadIdx.x;
    uint32_t c[BPT]; float s[BPT];
    uint32_t part_c = 0; float part_s = 0.f;
#pragma unroll
    for (int j = 0; j < BPT; ++j) {
        c[j] = g_cnt[t * BPT + j];
        s[j] = g_sum[t * BPT + j];
        part_c += c[j]; part_s += s[j];
    }
    if (t == 0) s_negsum = 0.f;
    scnt[t] = part_c; ssum[t] = part_s;
    __syncthreads();

    // Hillis-Steele suffix scan toward higher bins (larger losses)
    for (int off = 1; off < BLOCK; off <<= 1) {
        uint32_t v = scnt[t]; float w = ssum[t];
        if (t + off < BLOCK) { v += scnt[t + off]; w += ssum[t + off]; }
        __syncthreads();
        scnt[t] = v; ssum[t] = w;
        __syncthreads();
    }

    const uint32_t total = scnt[0];             // all negatives are binned
    const uint32_t posc  = *g_pos_cnt;
    // floor(pos*3.0) == 3*posc exactly in this regime; min with total
    uint64_t k3 = (uint64_t)posc * 3ull;
    uint32_t K = (k3 < (uint64_t)total) ? (uint32_t)k3 : total;

    const uint32_t above = scnt[t] - part_c;        // count in chunks > mine
    const float sum_above_chunks = ssum[t] - part_s;
    if (K > 0 && above < K && above + part_c >= K) {
        uint32_t cum = above; float lsum = 0.f; float negsum = 0.f;
#pragma unroll
        for (int j = BPT - 1; j >= 0; --j) {
            if (cum + c[j] >= K) {
                uint32_t rem = K - cum;
                float avg = c[j] ? (s[j] / (float)c[j]) : 0.f;
                negsum = sum_above_chunks + lsum + (float)rem * avg;
                break;
            }
            cum += c[j]; lsum += s[j];
        }
        s_negsum = negsum;   // exactly one thread qualifies
    }
    __syncthreads();
    if (t == 0) {
        float negsum = s_negsum;                 // stays 0 if K == 0
        float possum = *g_pos_sum;
        float denom = (float)posc + (float)K + 1e-6f;
        out[0] = (possum + negsum) / denom;
    }
}

extern "C" void kernel_launch(void* const* d_in, const int* in_sizes, int n_in,
                              void* d_out, int out_size, void* d_ws, size_t ws_size,
                              hipStream_t stream) {
    const float4* pred = (const float4*)d_in[0];
    const float4* gt   = (const float4*)d_in[1];
    const float4* mask = (const float4*)d_in[2];

    uint32_t* g_cnt     = (uint32_t*)d_ws;
    float*    g_sum     = (float*)((char*)d_ws + NBINS * 4);
    uint32_t* g_pos_cnt = (uint32_t*)((char*)d_ws + 2 * NBINS * 4);
    float*    g_pos_sum = (float*)((char*)d_ws + 2 * NBINS * 4 + 4);

    hipMemsetAsync(d_ws, 0, (2 * NBINS + 2) * 4, stream);
    bce_pass1<<<GRID1, BLOCK, 0, stream>>>(pred, gt, mask, g_cnt, g_sum,
                                           g_pos_cnt, g_pos_sum);
    bce_pass2<<<1, BLOCK, 0, stream>>>(g_cnt, g_sum, g_pos_cnt, g_pos_sum,
                                       (float*)d_out);
}